// Round 9
// baseline (277.663 us; speedup 1.0000x reference)
//
#include <hip/hip_runtime.h>
#include <hip/hip_bf16.h>
#include <math.h>
#include <stdint.h>

#define B 2
#define H 16
#define L 2048
#define D 64
#define NB 32
#define PTS 72            // P tile row stride in u16 (144 B)

typedef unsigned short u16;
typedef unsigned int u32;
typedef __attribute__((ext_vector_type(2))) unsigned int u32x2;
typedef __attribute__((ext_vector_type(8))) short s16x8;
typedef __attribute__((ext_vector_type(4))) float f32x4;

union FragU { s16x8 v; u32 u[4]; };

__device__ __forceinline__ u32 pkbf(float a, float b) {
  __hip_bfloat162 h = __float22bfloat162_rn(make_float2(a, b));  // v_cvt_pk_bf16_f32
  union { __hip_bfloat162 h; u32 u; } cv; cv.h = h; return cv.u;
}
__device__ __forceinline__ float bf2f(u32 u16bits) {
  union { u32 u; float f; } c; c.u = u16bits << 16; return c.f;
}
// split f32x4 -> packed hi (u32x2) + lo (u32x2), RNE both levels
__device__ __forceinline__ void split4(f32x4 p, u32x2& hi, u32x2& lo) {
  u32 h01 = pkbf(p[0], p[1]), h23 = pkbf(p[2], p[3]);
  float rx = p[0] - bf2f(h01 & 0xffffu);
  float ry = p[1] - bf2f(h01 >> 16);
  float rz = p[2] - bf2f(h23 & 0xffffu);
  float rw = p[3] - bf2f(h23 >> 16);
  hi = (u32x2){h01, h23};
  lo = (u32x2){pkbf(rx, ry), pkbf(rz, rw)};
}
__device__ __forceinline__ f32x4 ntld4(const float* p) {
  return __builtin_nontemporal_load((const f32x4*)p);
}
__device__ __forceinline__ void ntst4(float* p, f32x4 v) {
  __builtin_nontemporal_store(v, (f32x4*)p);
}

// ---------------------------------------------------------------------------
// k_prep: single pass over K (col-sums + split + rownorm), V transpose+split.
// nt loads for k/v; plane writes cacheable (same XCD will read them).
// ---------------------------------------------------------------------------
__global__ __launch_bounds__(256) void k_prep(const float* __restrict__ k,
                                              const float* __restrict__ v,
                                              float* __restrict__ ksum,
                                              u16* __restrict__ khi_g,
                                              u16* __restrict__ klo_g,
                                              u16* __restrict__ vthi_g,
                                              u16* __restrict__ vtlo_g,
                                              float* __restrict__ kbmax) {
  int blk = blockIdx.x, bh = blk >> 5, j = blk & 31, t = threadIdx.x;
  __shared__ float vt[64 * 65];
  __shared__ float pk_[16][64];
  __shared__ unsigned bmaxS;
  if (t == 0) bmaxS = 0u;
  size_t base = (size_t)blk * 4096;
  int c4 = (t & 15) * 4, rg = t >> 4;
  float cs0 = 0.f, cs1 = 0.f, cs2 = 0.f, cs3 = 0.f;
  float rmax = 0.f;
#pragma unroll
  for (int it = 0; it < 4; ++it) {
    int r = rg + 16 * it;
    f32x4 f = ntld4(k + base + r * 64 + c4);
    cs0 += f[0]; cs1 += f[1]; cs2 += f[2]; cs3 += f[3];
    u32x2 hi, lo; split4(f, hi, lo);
    *(u32x2*)(khi_g + base + r * 64 + c4) = hi;
    *(u32x2*)(klo_g + base + r * 64 + c4) = lo;
    float ssq = f[0]*f[0] + f[1]*f[1] + f[2]*f[2] + f[3]*f[3];
    ssq += __shfl_xor(ssq, 1); ssq += __shfl_xor(ssq, 2);
    ssq += __shfl_xor(ssq, 4); ssq += __shfl_xor(ssq, 8);
    if ((t & 15) == 0) rmax = fmaxf(rmax, ssq);
    f32x4 g2 = ntld4(v + base + r * 64 + c4);
    vt[(c4 + 0) * 65 + r] = g2[0];
    vt[(c4 + 1) * 65 + r] = g2[1];
    vt[(c4 + 2) * 65 + r] = g2[2];
    vt[(c4 + 3) * 65 + r] = g2[3];
  }
  pk_[rg][c4] = cs0; pk_[rg][c4 + 1] = cs1; pk_[rg][c4 + 2] = cs2; pk_[rg][c4 + 3] = cs3;
  if ((t & 15) == 0) atomicMax(&bmaxS, __float_as_uint(rmax));
  __syncthreads();
  if (t < 64) {
    float s = 0.f;
#pragma unroll
    for (int g = 0; g < 16; ++g) s += pk_[g][t];
    ksum[(size_t)blk * 64 + t] = s;
  }
  if (t == 0) kbmax[blk] = __uint_as_float(bmaxS);
  for (int it = 0; it < 2; ++it) {
    int idx = t + 256 * it, d = idx >> 3, s8 = (idx & 7) * 8;
    const float* vr = &vt[d * 65 + s8];
    f32x4 f0 = {vr[0], vr[1], vr[2], vr[3]};
    f32x4 f1 = {vr[4], vr[5], vr[6], vr[7]};
    u32x2 h0, l0, h1, l1;
    split4(f0, h0, l0); split4(f1, h1, l1);
    size_t o = (size_t)bh * 131072 + (size_t)d * 2048 + j * 64 + s8;
    *(u32x2*)(vthi_g + o) = h0; *(u32x2*)(vthi_g + o + 4) = h1;
    *(u32x2*)(vtlo_g + o) = l0; *(u32x2*)(vtlo_g + o + 4) = l1;
  }
}

// ---------------------------------------------------------------------------
// k_attn: 2 q-blocks per WG, union-mask sweep, LDS-staged Q (nt), deep prefetch
// LDS map (bytes):
//   0      P/QF region: QF = f32[2][64][68] (setup) aliases 4x P planes (pass B)
//   36864  rbm qb0/qb1 (2 x 64*33 u32)  53760 MS[128]  54272 linv[128]
//   54784  lpart[4][128]  56832 qm[2][64]  57344 flags[8]
// ---------------------------------------------------------------------------
#define RBM_OFF 36864
#define MS_OFF 53760
#define LINV_OFF 54272
#define LPART_OFF 54784
#define QM_OFF 56832
#define FLG_OFF 57344

__global__ __launch_bounds__(256, 2) void k_attn(
    const float* __restrict__ q,
    const float* __restrict__ ksum,
    const u16* __restrict__ khi_g, const u16* __restrict__ klo_g,
    const u16* __restrict__ vthi_g, const u16* __restrict__ vtlo_g,
    const float* __restrict__ cdfthreshd, const float* __restrict__ simthreshd1,
    const float* __restrict__ pvthreshd, const float* __restrict__ kbmax,
    float* __restrict__ out) {
  int blk = blockIdx.x, bh = blk >> 4, ip = blk & 15, h = bh & (H - 1);
  int t = threadIdx.x, lane = t & 63, w = t >> 6;
  int m16 = lane & 15, quad = lane >> 4;

  __shared__ __align__(16) uint8_t smem[57376];
  u16*   pbase = (u16*)smem;
  float* qfp   = (float*)smem;                   // QF(qb) = qfp + qb*4352 (64x68)
  u32*   rbm0  = (u32*)(smem + RBM_OFF);
  float* MS    = (float*)(smem + MS_OFF);
  float* linvS = (float*)(smem + LINV_OFF);
  float* lpart = (float*)(smem + LPART_OFF);
  float* qmS   = (float*)(smem + QM_OFF);
  int*   flg   = (int*)(smem + FLG_OFF);
#define PHQ(qb) (pbase + (qb) * 9216)
#define PLQ(qb) (pbase + 4608 + (qb) * 9216)

  const float* qg0 = q + ((size_t)bh * L + (size_t)(2 * ip) * 64) * D;
  const u16* kh = khi_g + (size_t)bh * (L * D);
  const u16* kl = klo_g + (size_t)bh * (L * D);
  const u16* vh = vthi_g + (size_t)bh * (L * D);
  const u16* vl = vtlo_g + (size_t)bh * (L * D);

  // ---- stage Q to LDS once (nontemporal), init rbm ----
  for (int it = 0; it < 8; ++it) {
    int idx = t + 256 * it;
    int qb = idx >> 10, rem = idx & 1023;
    int r = rem >> 4, c4 = (rem & 15) * 4;
    f32x4 f = ntld4(qg0 + qb * 4096 + r * 64 + c4);
    *(f32x4*)&qfp[qb * 4352 + r * 68 + c4] = f;
  }
  for (int e = t; e < 2 * 64 * 33; e += 256) rbm0[e] = 0x7F800000u;
  __syncthreads();

  // ---- Q B-fragments from LDS (f32 -> split, registers) ----
  s16x8 qhf[2][4][2], qlf[2][4][2];
#pragma unroll
  for (int qb = 0; qb < 2; ++qb)
#pragma unroll
    for (int nt = 0; nt < 4; ++nt)
#pragma unroll
      for (int ks = 0; ks < 2; ++ks) {
        const float* p0 = qfp + qb * 4352 + (16 * nt + m16) * 68 + ks * 32 + quad * 8;
        f32x4 a = *(const f32x4*)p0;
        f32x4 b2 = *(const f32x4*)(p0 + 4);
        u32x2 ha, la, hb, lb;
        split4(a, ha, la); split4(b2, hb, lb);
        FragU fh, fl;
        fh.u[0] = ha[0]; fh.u[1] = ha[1]; fh.u[2] = hb[0]; fh.u[3] = hb[1];
        fl.u[0] = la[0]; fl.u[1] = la[1]; fl.u[2] = lb[0]; fl.u[3] = lb[1];
        qhf[qb][nt][ks] = fh.v; qlf[qb][nt][ks] = fl.v;
      }

  // ---- phase 1: qm per qb (w0,w2), kmax2 (w1) ----
  if (w == 0 || w == 2) {
    int qb = w >> 1;
    float s = 0.f;
    for (int r = 0; r < 64; ++r) s += qfp[qb * 4352 + r * 68 + lane];
    qmS[qb * 64 + lane] = s * (1.f / 64.f);
  }
  if (w == 1) {
    float m = (lane < 32) ? kbmax[bh * 32 + lane] : 0.f;
    for (int off = 16; off; off >>= 1) m = fmaxf(m, __shfl_xor(m, off, 32));
    if (lane == 0) ((float*)flg)[6] = m;
  }
  __syncthreads();

  // ---- phase 2: CDF keep (w0:qb0, w2:qb1); pooled cos + M (w1:qb0, w3:qb1) ----
  bool keepj = false;
  if ((w == 0 || w == 2) && lane < 32) {
    int qb = w >> 1, j = lane;
    const float* qmv = qmS + qb * 64;
    const float* ksp = ksum + (size_t)bh * NB * 64 + j * 64;
    float sv = 0.f;
    for (int d = 0; d < 64; ++d) sv += qmv[d] * ksp[d];
    sv *= (1.f / 64.f) * 0.125f;     // mean shift cancels in softmax
    float mx = sv;
    for (int off = 16; off; off >>= 1) mx = fmaxf(mx, __shfl_xor(mx, off, 32));
    float p = expf(sv - mx);
    float sum = p;
    for (int off = 16; off; off >>= 1) sum += __shfl_xor(sum, off, 32);
    p /= sum;
    float excl = 0.f;
    for (int u = 0; u < 32; ++u) {
      float pu = __shfl(p, u, 32);
      if ((pu > p) || (pu == p && u < j)) excl += pu;
    }
    keepj = excl < cdfthreshd[h];
  }
  if (w == 1 || w == 3) {
    int qb = w >> 1, r = lane;
    const float* qmv = qmS + qb * 64;
    float kmax2 = ((float*)flg)[6];
    float dot = 0.f, qn2 = 0.f, qmn2 = 0.f;
    for (int d = 0; d < 64; ++d) {
      float a = qfp[qb * 4352 + r * 68 + d], b2 = qmv[d];
      dot += a * b2; qn2 += a * a; qmn2 += b2 * b2;
    }
    float cs = dot / (sqrtf(qn2) * sqrtf(qmn2) + 1e-6f);
    float su = cs;
    for (int off = 32; off; off >>= 1) su += __shfl_xor(su, off);
    if (lane == 0) flg[qb] = (su * (1.f / 64.f)) > simthreshd1[h];
    MS[qb * 64 + r] = sqrtf(qn2 * kmax2) * 0.125f;  // M_r >= |s| (Cauchy-Schwarz)
  }
  __syncthreads();
  if ((w == 0 || w == 2) && lane < 32) {
    int qb = w >> 1;
    bool bit = keepj || !flg[qb] || (lane == 0);
    unsigned long long bal = __ballot(bit);
    if (lane == 0) flg[2 + qb] = (int)(u32)bal;
  }
  __syncthreads();
  u32 mw0 = (u32)flg[2], mw1 = (u32)flg[3];

  float Mq[2][4];
#pragma unroll
  for (int qb = 0; qb < 2; ++qb)
#pragma unroll
    for (int nt = 0; nt < 4; ++nt) Mq[qb][nt] = MS[qb * 64 + 16 * nt + m16];

  // ---- Pass A: union sweep, depth-2 K prefetch ----
  float lp[2][4] = {{0.f,0.f,0.f,0.f},{0.f,0.f,0.f,0.f}};
  {
    u32 mwU = mw0 | mw1;
    u32 rm_ = mwU;
    int j0 = (int)__builtin_ctz(rm_); rm_ &= rm_ - 1;
    s16x8 ka[2][2], kb_[2][2], kc[2][2];
    {
      const u16* kr0 = kh + (size_t)(j0 * 64 + 16 * w + m16) * 64 + quad * 8;
      const u16* kl0 = kl + (size_t)(j0 * 64 + 16 * w + m16) * 64 + quad * 8;
#pragma unroll
      for (int ks = 0; ks < 2; ++ks) {
        ka[ks][0] = *(const s16x8*)(kr0 + ks * 32);
        ka[ks][1] = *(const s16x8*)(kl0 + ks * 32);
      }
    }
    int j1 = -1;
    if (rm_) {
      j1 = (int)__builtin_ctz(rm_); rm_ &= rm_ - 1;
      const u16* nr = kh + (size_t)(j1 * 64 + 16 * w + m16) * 64 + quad * 8;
      const u16* nl = kl + (size_t)(j1 * 64 + 16 * w + m16) * 64 + quad * 8;
#pragma unroll
      for (int ks = 0; ks < 2; ++ks) {
        kb_[ks][0] = *(const s16x8*)(nr + ks * 32);
        kb_[ks][1] = *(const s16x8*)(nl + ks * 32);
      }
    }
    for (;;) {
      int j2 = -1;
      if (rm_) {
        j2 = (int)__builtin_ctz(rm_); rm_ &= rm_ - 1;
        const u16* nr = kh + (size_t)(j2 * 64 + 16 * w + m16) * 64 + quad * 8;
        const u16* nl = kl + (size_t)(j2 * 64 + 16 * w + m16) * 64 + quad * 8;
#pragma unroll
        for (int ks = 0; ks < 2; ++ks) {
          kc[ks][0] = *(const s16x8*)(nr + ks * 32);
          kc[ks][1] = *(const s16x8*)(nl + ks * 32);
        }
      }
#pragma unroll
      for (int qb = 0; qb < 2; ++qb) {
        u32 mm = qb ? mw1 : mw0;
        if (!((mm >> j0) & 1u)) continue;
        f32x4 acc[4];
#pragma unroll
        for (int nt = 0; nt < 4; ++nt) acc[nt] = (f32x4){0.f, 0.f, 0.f, 0.f};
#pragma unroll
        for (int ks = 0; ks < 2; ++ks)
#pragma unroll
          for (int nt = 0; nt < 4; ++nt) {
            acc[nt] = __builtin_amdgcn_mfma_f32_16x16x32_bf16(ka[ks][0], qhf[qb][nt][ks], acc[nt], 0, 0, 0);
            acc[nt] = __builtin_amdgcn_mfma_f32_16x16x32_bf16(ka[ks][1], qhf[qb][nt][ks], acc[nt], 0, 0, 0);
            acc[nt] = __builtin_amdgcn_mfma_f32_16x16x32_bf16(ka[ks][0], qlf[qb][nt][ks], acc[nt], 0, 0, 0);
          }
#pragma unroll
        for (int nt = 0; nt < 4; ++nt) {
          float vmax = -1e30f;
#pragma unroll
          for (int reg = 0; reg < 4; ++reg) {
            float s = acc[nt][reg] * 0.125f - Mq[qb][nt];
            lp[qb][nt] += __expf(s);
            vmax = fmaxf(vmax, s);
          }
          vmax = fmaxf(vmax, __shfl_xor(vmax, 16));
          vmax = fmaxf(vmax, __shfl_xor(vmax, 32));
          if (quad == 0)
            atomicMin(rbm0 + qb * (64 * 33) + (16 * nt + m16) * 33 + j0,
                      __float_as_uint(fmaxf(-vmax, 0.f)));
        }
      }
      if (j1 < 0) break;
#pragma unroll
      for (int ks = 0; ks < 2; ++ks) {
        ka[ks][0] = kb_[ks][0]; ka[ks][1] = kb_[ks][1];
        kb_[ks][0] = kc[ks][0]; kb_[ks][1] = kc[ks][1];
      }
      j0 = j1; j1 = j2;
    }
  }
#pragma unroll
  for (int qb = 0; qb < 2; ++qb)
#pragma unroll
    for (int nt = 0; nt < 4; ++nt) {
      float s = lp[qb][nt];
      s += __shfl_xor(s, 16); s += __shfl_xor(s, 32);
      if (quad == 0) lpart[w * 128 + qb * 64 + 16 * nt + m16] = s;
    }
  __syncthreads();
  if (t < 128) linvS[t] = 1.f / (lpart[t] + lpart[128 + t] + lpart[256 + t] + lpart[384 + t]);
  __syncthreads();

  // ---- PV gate: wave0 -> qb0, wave1 -> qb1 ----
  if (w < 2 && lane < 32) {
    u32 mm = w ? mw1 : mw0;
    bool keep = (mm >> lane) & 1u;
    if (keep && lane != 0) {
      float thr = pvthreshd[h] * 1e-3f;
      const float* lin = linvS + w * 64;
      const u32* rb = rbm0 + w * (64 * 33);
      float mp = 0.f;
      for (int r = 0; r < 64; ++r) {
        float key = __uint_as_float(rb[r * 33 + lane]);
        mp = fmaxf(mp, __expf(-key) * lin[r]);
      }
      keep = mp >= thr;
    }
    unsigned long long bal = __ballot(keep);
    if (lane == 0) flg[4 + w] = (int)(u32)bal;
  }
  __syncthreads();
  u32 gm0 = (u32)flg[4], gm1 = (u32)flg[5];

  // ---- Pass B: loop-top K+V prefetch for next j ----
  float linq[2][4];
#pragma unroll
  for (int qb = 0; qb < 2; ++qb)
#pragma unroll
    for (int nt = 0; nt < 4; ++nt) linq[qb][nt] = linvS[qb * 64 + 16 * nt + m16];
  f32x4 oacc[2][4];
#pragma unroll
  for (int qb = 0; qb < 2; ++qb)
#pragma unroll
    for (int nt = 0; nt < 4; ++nt) oacc[qb][nt] = (f32x4){0.f, 0.f, 0.f, 0.f};

  {
    u32 g2 = gm0 | gm1;
    int j = -1;
    s16x8 ka[2][2], va[2][2], kan[2][2], van[2][2];
    if (g2) {
      j = (int)__builtin_ctz(g2); g2 &= g2 - 1;
      const u16* kr0 = kh + (size_t)(j * 64 + 16 * w + m16) * 64 + quad * 8;
      const u16* kl0 = kl + (size_t)(j * 64 + 16 * w + m16) * 64 + quad * 8;
      const u16* vr0 = vh + (size_t)(16 * w + m16) * L + j * 64 + quad * 8;
      const u16* vl0 = vl + (size_t)(16 * w + m16) * L + j * 64 + quad * 8;
#pragma unroll
      for (int ks = 0; ks < 2; ++ks) {
        ka[ks][0] = *(const s16x8*)(kr0 + ks * 32);
        ka[ks][1] = *(const s16x8*)(kl0 + ks * 32);
        va[ks][0] = *(const s16x8*)(vr0 + ks * 32);
        va[ks][1] = *(const s16x8*)(vl0 + ks * 32);
      }
    }
    while (j >= 0) {
      // prefetch next j's K and V at loop top (max lead time)
      int nj = -1;
      if (g2) {
        nj = (int)__builtin_ctz(g2); g2 &= g2 - 1;
        const u16* nr = kh + (size_t)(nj * 64 + 16 * w + m16) * 64 + quad * 8;
        const u16* nl = kl + (size_t)(nj * 64 + 16 * w + m16) * 64 + quad * 8;
        const u16* vr0 = vh + (size_t)(16 * w + m16) * L + nj * 64 + quad * 8;
        const u16* vl0 = vl + (size_t)(16 * w + m16) * L + nj * 64 + quad * 8;
#pragma unroll
        for (int ks = 0; ks < 2; ++ks) {
          kan[ks][0] = *(const s16x8*)(nr + ks * 32);
          kan[ks][1] = *(const s16x8*)(nl + ks * 32);
          van[ks][0] = *(const s16x8*)(vr0 + ks * 32);
          van[ks][1] = *(const s16x8*)(vl0 + ks * 32);
        }
      }
      int in0 = (gm0 >> j) & 1, in1 = (gm1 >> j) & 1;
      // S for qb0
      f32x4 acc[4];
      if (in0) {
#pragma unroll
        for (int nt = 0; nt < 4; ++nt) acc[nt] = (f32x4){0.f, 0.f, 0.f, 0.f};
#pragma unroll
        for (int ks = 0; ks < 2; ++ks)
#pragma unroll
          for (int nt = 0; nt < 4; ++nt) {
            acc[nt] = __builtin_amdgcn_mfma_f32_16x16x32_bf16(ka[ks][0], qhf[0][nt][ks], acc[nt], 0, 0, 0);
            acc[nt] = __builtin_amdgcn_mfma_f32_16x16x32_bf16(ka[ks][1], qhf[0][nt][ks], acc[nt], 0, 0, 0);
            acc[nt] = __builtin_amdgcn_mfma_f32_16x16x32_bf16(ka[ks][0], qlf[0][nt][ks], acc[nt], 0, 0, 0);
          }
      }
      __syncthreads();   // prior PV reads of P buffers complete
      if (in0) {
#pragma unroll
        for (int nt = 0; nt < 4; ++nt) {
          f32x4 pv;
          pv[0] = __expf(acc[nt][0] * 0.125f - Mq[0][nt]) * linq[0][nt];
          pv[1] = __expf(acc[nt][1] * 0.125f - Mq[0][nt]) * linq[0][nt];
          pv[2] = __expf(acc[nt][2] * 0.125f - Mq[0][nt]) * linq[0][nt];
          pv[3] = __expf(acc[nt][3] * 0.125f - Mq[0][nt]) * linq[0][nt];
          u32x2 hi, lo; split4(pv, hi, lo);
          int off = (16 * nt + m16) * PTS + 16 * w + 4 * quad;
          *(u32x2*)(PHQ(0) + off) = hi;
          *(u32x2*)(PLQ(0) + off) = lo;
        }
      }
      // S for qb1 (fills the barrier window), then P1 write
      if (in1) {
#pragma unroll
        for (int nt = 0; nt < 4; ++nt) acc[nt] = (f32x4){0.f, 0.f, 0.f, 0.f};
#pragma unroll
        for (int ks = 0; ks < 2; ++ks)
#pragma unroll
          for (int nt = 0; nt < 4; ++nt) {
            acc[nt] = __builtin_amdgcn_mfma_f32_16x16x32_bf16(ka[ks][0], qhf[1][nt][ks], acc[nt], 0, 0, 0);
            acc[nt] = __builtin_amdgcn_mfma_f32_16x16x32_bf16(ka[ks][1], qhf[1][nt][ks], acc[nt], 0, 0, 0);
            acc[nt] = __builtin_amdgcn_mfma_f32_16x16x32_bf16(ka[ks][0], qlf[1][nt][ks], acc[nt], 0, 0, 0);
          }
#pragma unroll
        for (int nt = 0; nt < 4; ++nt) {
          f32x4 pv;
          pv[0] = __expf(acc[nt][0] * 0.125f - Mq[1][nt]) * linq[1][nt];
          pv[1] = __expf(acc[nt][1] * 0.125f - Mq[1][nt]) * linq[1][nt];
          pv[2] = __expf(acc[nt][2] * 0.125f - Mq[1][nt]) * linq[1][nt];
          pv[3] = __expf(acc[nt][3] * 0.125f - Mq[1][nt]) * linq[1][nt];
          u32x2 hi, lo; split4(pv, hi, lo);
          int off = (16 * nt + m16) * PTS + 16 * w + 4 * quad;
          *(u32x2*)(PHQ(1) + off) = hi;
          *(u32x2*)(PLQ(1) + off) = lo;
        }
      }
      __syncthreads();
      // PV for both q-blocks (va shared)
#pragma unroll
      for (int qb = 0; qb < 2; ++qb) {
        if (!(qb ? in1 : in0)) continue;
        const u16* ph_ = PHQ(qb);
        const u16* pl_ = PLQ(qb);
#pragma unroll
        for (int ks = 0; ks < 2; ++ks)
#pragma unroll
          for (int nt = 0; nt < 4; ++nt) {
            s16x8 pbh = *(const s16x8*)(ph_ + (16 * nt + m16) * PTS + ks * 32 + quad * 8);
            s16x8 pbl = *(const s16x8*)(pl_ + (16 * nt + m16) * PTS + ks * 32 + quad * 8);
            oacc[qb][nt] = __builtin_amdgcn_mfma_f32_16x16x32_bf16(va[ks][0], pbh, oacc[qb][nt], 0, 0, 0);
            oacc[qb][nt] = __builtin_amdgcn_mfma_f32_16x16x32_bf16(va[ks][1], pbh, oacc[qb][nt], 0, 0, 0);
            oacc[qb][nt] = __builtin_amdgcn_mfma_f32_16x16x32_bf16(va[ks][0], pbl, oacc[qb][nt], 0, 0, 0);
          }
      }
#pragma unroll
      for (int ks = 0; ks < 2; ++ks) {
        ka[ks][0] = kan[ks][0]; ka[ks][1] = kan[ks][1];
        va[ks][0] = van[ks][0]; va[ks][1] = van[ks][1];
      }
      j = nj;
    }
  }

  // ---- store O nontemporal: q-row = 16nt+m16, d = 16w+4quad (f32x4) ----
#pragma unroll
  for (int qb = 0; qb < 2; ++qb) {
    float* ob = out + ((size_t)bh * L + (size_t)(2 * ip + qb) * 64) * D;
#pragma unroll
    for (int nt = 0; nt < 4; ++nt)
      ntst4(ob + (16 * nt + m16) * 64 + 16 * w + 4 * quad, oacc[qb][nt]);
  }
}

// ---------------------------------------------------------------------------
extern "C" void kernel_launch(void* const* d_in, const int* in_sizes, int n_in,
                              void* d_out, int out_size, void* d_ws, size_t ws_size,
                              hipStream_t stream) {
  (void)in_sizes; (void)n_in; (void)out_size; (void)ws_size;
  const float* q   = (const float*)d_in[0];
  const float* k   = (const float*)d_in[1];
  const float* v   = (const float*)d_in[2];
  const float* cdf = (const float*)d_in[3];
  const float* sim = (const float*)d_in[4];
  const float* pvt = (const float*)d_in[5];
  float* out = (float*)d_out;

  uint8_t* w8 = (uint8_t*)d_ws;
  float* ksum  = (float*)w8;                          // 1024*64 f (256 KB)
  float* kbmax = (float*)(w8 + 262144);               // 1024 f (4 KB)
  u16* khi_g  = (u16*)(w8 + 266240);                  // 4 planes x 8 MB
  u16* klo_g  = khi_g + (size_t)B * H * L * D;
  u16* vthi_g = klo_g + (size_t)B * H * L * D;
  u16* vtlo_g = vthi_g + (size_t)B * H * L * D;

  k_prep<<<B * H * NB, 256, 0, stream>>>(k, v, ksum, khi_g, klo_g, vthi_g, vtlo_g, kbmax);
  k_attn<<<B * H * NB / 2, 256, 0, stream>>>(q, ksum, khi_g, klo_g, vthi_g, vtlo_g,
                                             cdf, sim, pvt, kbmax, out);
}